// Round 5
// baseline (1048.278 us; speedup 1.0000x reference)
//
#include <hip/hip_runtime.h>

#define ZDIM 4096
#define DIN  256
#define DTS  2048
#define DOUT 256
#define CDIM 65536
#define SPLIT 8
#define CHUNK (CDIM / SPLIT)   // 8192 c per chunk = 32 i-blocks of 256 j

typedef float fv4 __attribute__((ext_vector_type(4)));
typedef __bf16 bv8 __attribute__((ext_vector_type(8)));
typedef unsigned short u16;
typedef u16 uv8 __attribute__((ext_vector_type(8)));

union BC  { __bf16 b; u16 u; };
union VC8 { uv8 u; bv8 b; };
union FU  { unsigned u; float f; };

static __device__ __forceinline__ u16  f2b(float f){ BC c; c.b=(__bf16)f; return c.u; }
static __device__ __forceinline__ float bu(u16 v){ FU c; c.u = ((unsigned)v) << 16; return c.f; }
static __device__ __forceinline__ bv8  asb(uv8 x){ VC8 c; c.u=x; return c.b; }
static __device__ __forceinline__ uv8  pack8(fv4 a, fv4 b){
  uv8 p;
  p[0]=f2b(a[0]); p[1]=f2b(a[1]); p[2]=f2b(a[2]); p[3]=f2b(a[3]);
  p[4]=f2b(b[0]); p[5]=f2b(b[1]); p[6]=f2b(b[2]); p[7]=f2b(b[3]);
  return p;
}

// ---------------------------------------------------------------------------
// Kernel 1: Kmat[k][c] = sum_t W[k][t] * T[t][c]   (bf16 output in ws)
// memory-bound: streams 512 MB of T once. Unchanged (attribution).
// ---------------------------------------------------------------------------
__global__ __launch_bounds__(512, 2) void k_wt(const float* __restrict__ W,
                                               const float* __restrict__ T,
                                               u16* __restrict__ Km) {
  __shared__ u16 Al[256 * 40];   // W tile [k][t], padded stride 40
  __shared__ u16 Bl[32 * 128];   // T tile [t][c], row-major
  const int tid  = threadIdx.x;
  const int lane = tid & 63;
  const int wave = tid >> 6;
  const int wk = (wave >> 1) * 64;
  const int wc = (wave & 1) * 64;
  const int cb = blockIdx.x * 128;
  const int ar = lane & 15, tg = lane >> 4;

  fv4 acc[4][4];
#pragma unroll
  for (int m = 0; m < 4; ++m)
#pragma unroll
    for (int n = 0; n < 4; ++n)
#pragma unroll
      for (int r = 0; r < 4; ++r) acc[m][n][r] = 0.f;

  for (int t0 = 0; t0 < DTS; t0 += 32) {
#pragma unroll
    for (int p = 0; p < 2; ++p) {
      int oct = tid + p * 512;
      int kr = oct >> 2, ts = (oct & 3) * 8;
      const float* src = W + (size_t)kr * DTS + t0 + ts;
      fv4 a = *(const fv4*)src, b = *(const fv4*)(src + 4);
      *(uv8*)&Al[kr * 40 + ts] = pack8(a, b);
    }
    {
      int tr = tid >> 4, co = (tid & 15) * 8;
      const float* src = T + (size_t)(t0 + tr) * CDIM + cb + co;
      fv4 a = *(const fv4*)src, b = *(const fv4*)(src + 4);
      *(uv8*)&Bl[tr * 128 + co] = pack8(a, b);
    }
    __syncthreads();
    bv8 af[4];
#pragma unroll
    for (int m = 0; m < 4; ++m)
      af[m] = asb(*(const uv8*)&Al[(wk + m * 16 + ar) * 40 + tg * 8]);
#pragma unroll
    for (int n = 0; n < 4; ++n) {
      uv8 bu2;
#pragma unroll
      for (int e = 0; e < 8; ++e)
        bu2[e] = Bl[(tg * 8 + e) * 128 + wc + n * 16 + ar];
      bv8 bf = asb(bu2);
#pragma unroll
      for (int m = 0; m < 4; ++m)
        acc[m][n] = __builtin_amdgcn_mfma_f32_16x16x32_bf16(af[m], bf, acc[m][n], 0, 0, 0);
    }
    __syncthreads();
  }
#pragma unroll
  for (int m = 0; m < 4; ++m)
#pragma unroll
    for (int n = 0; n < 4; ++n)
#pragma unroll
      for (int r = 0; r < 4; ++r) {
        int kr = wk + m * 16 + tg * 4 + r;
        int cc = cb + wc + n * 16 + ar;
        Km[(size_t)kr * CDIM + cc] = f2b(acc[m][n][r]);
      }
}

// ---------------------------------------------------------------------------
// Kernel 2 v5: out[z,k] = sum_i sum_j (x_i*x_j) Km[k, i*256+j]
// Single accumulator acc[4][2] (32 VGPR): xi folded into A-frag per step
// (afp = bf16(xi * xj), built from register af[4][8] -- no mas/aci split,
// no spill: ~210 VGPR total).
// B staged to LDS coalesced, double-buffered Bl[2][256][40], reg-staged
// (loads at step top, ds_writes after MFMAs), ONE barrier per 32-j step.
// grid 512: bid&7 = split chunk (XCD-affine), bid>>3 = z-panel of 64
// ---------------------------------------------------------------------------
__global__ __launch_bounds__(512, 2) void k_bil(const float* __restrict__ X,
                                                const u16* __restrict__ Km,
                                                float* __restrict__ P) {
  __shared__ u16 Bl[2][256 * 40];   // 2 x 20 KB, [k][32 j] pad 40
  __shared__ float Xt[32 * 64];     // 8 KB: Xt[i][z] = X[z0+z][i0+i]
  const int tid  = threadIdx.x;
  const int lane = tid & 63;
  const int wave = tid >> 6;
  const int wkk  = wave * 32;
  const int bid  = blockIdx.x;
  const int s    = bid & 7;
  const int z0   = (bid >> 3) * 64;
  const int i0   = s * 32;
  const int cs   = s * CHUNK;
  const int ar = lane & 15, tg = lane >> 4;

  // one-time Xt stage
  for (int idx = tid; idx < 32 * 64; idx += 512) {
    int ii = idx >> 6, z = idx & 63;
    Xt[idx] = X[(size_t)(z0 + z) * DIN + i0 + ii];
  }

  // preload A-base fragments: af[m][js] = bf16(x[z0+m*16+ar][js*32+tg*8..+8])
  uv8 af[4][8];
#pragma unroll
  for (int m = 0; m < 4; ++m) {
    const float* row = X + (size_t)(z0 + m * 16 + ar) * DIN;
#pragma unroll
    for (int js = 0; js < 8; ++js) {
      const float* src = row + js * 32 + tg * 8;
      fv4 a = *(const fv4*)src, b = *(const fv4*)(src + 4);
      af[m][js] = pack8(a, b);
    }
  }

  // B staging map: thread t -> k row t>>1, 16-elem j-seg (t&1)*16
  const int sk = tid >> 1, sj = (tid & 1) * 16;
  const u16* gb = Km + (size_t)sk * CDIM + cs + sj;

  // prologue: stage step 0 into Bl[0]
  {
    uv8 a = *(const uv8*)gb, b = *(const uv8*)(gb + 8);
    *(uv8*)&Bl[0][sk * 40 + sj]     = a;
    *(uv8*)&Bl[0][sk * 40 + sj + 8] = b;
  }
  __syncthreads();

  fv4 acc[4][2];
#pragma unroll
  for (int m = 0; m < 4; ++m)
#pragma unroll
    for (int n = 0; n < 2; ++n)
#pragma unroll
      for (int r = 0; r < 4; ++r) acc[m][n][r] = 0.f;

  int buf = 0;
  for (int i = 0; i < 32; ++i) {
    float xi[4];
#pragma unroll
    for (int m = 0; m < 4; ++m) xi[m] = Xt[i * 64 + m * 16 + ar];
#pragma unroll
    for (int js = 0; js < 8; ++js) {
      const int st = i * 8 + js;
      const bool stg = (st < 255);
      uv8 g0, g1;
      if (stg) {                       // issue next-step loads early
        const u16* p = gb + (size_t)(st + 1) * 32;
        g0 = *(const uv8*)p;
        g1 = *(const uv8*)(p + 8);
      }
      bv8 bf0 = asb(*(const uv8*)&Bl[buf][(wkk +      ar) * 40 + tg * 8]);
      bv8 bf1 = asb(*(const uv8*)&Bl[buf][(wkk + 16 + ar) * 40 + tg * 8]);
#pragma unroll
      for (int m = 0; m < 4; ++m) {
        uv8 ap;
#pragma unroll
        for (int e = 0; e < 8; ++e) ap[e] = f2b(xi[m] * bu(af[m][js][e]));
        bv8 apb = asb(ap);
        acc[m][0] = __builtin_amdgcn_mfma_f32_16x16x32_bf16(apb, bf0, acc[m][0], 0, 0, 0);
        acc[m][1] = __builtin_amdgcn_mfma_f32_16x16x32_bf16(apb, bf1, acc[m][1], 0, 0, 0);
      }
      if (stg) {                       // write-late into the other buffer
        u16* d = &Bl[buf ^ 1][sk * 40 + sj];
        *(uv8*)d       = g0;
        *(uv8*)(d + 8) = g1;
      }
      __syncthreads();
      buf ^= 1;
    }
  }

  float* dst = P + (size_t)s * (ZDIM * DOUT) + (size_t)z0 * DOUT;
#pragma unroll
  for (int m = 0; m < 4; ++m)
#pragma unroll
    for (int n = 0; n < 2; ++n)
#pragma unroll
      for (int r = 0; r < 4; ++r)
        dst[(size_t)(m * 16 + tg * 4 + r) * DOUT + wkk + n * 16 + ar] = acc[m][n][r];
}

// ---------------------------------------------------------------------------
// Kernel 3: out[z][k] = sum_s partial[s][z][k]
// ---------------------------------------------------------------------------
__global__ __launch_bounds__(256) void k_red(const float* __restrict__ P,
                                             float* __restrict__ O) {
  size_t idx = ((size_t)blockIdx.x * 256 + threadIdx.x) * 4;
  fv4 acc;
#pragma unroll
  for (int r = 0; r < 4; ++r) acc[r] = 0.f;
#pragma unroll
  for (int p = 0; p < SPLIT; ++p)
    acc += *(const fv4*)&P[(size_t)p * (ZDIM * DOUT) + idx];
  *(fv4*)&O[idx] = acc;
}

extern "C" void kernel_launch(void* const* d_in, const int* in_sizes, int n_in,
                              void* d_out, int out_size, void* d_ws, size_t ws_size,
                              hipStream_t stream) {
  const float* feat = (const float*)d_in[0];   // [4096, 256]
  const float* T    = (const float*)d_in[1];   // [2048, 65536]
  const float* W    = (const float*)d_in[2];   // [256, 2048]
  float* out = (float*)d_out;                  // [4096, 256]

  u16*   Km = (u16*)d_ws;                                        // 32 MB bf16 Kmat
  float* P  = (float*)((char*)d_ws + (size_t)DOUT * CDIM * 2);   // 32 MB partials

  k_wt <<<dim3(512),  dim3(512), 0, stream>>>(W, T, Km);
  k_bil<<<dim3(512),  dim3(512), 0, stream>>>(feat, Km, P);
  k_red<<<dim3(1024), dim3(256), 0, stream>>>(P, out);
}

// Round 6
// 929.581 us; speedup vs baseline: 1.1277x; 1.1277x over previous
//
#include <hip/hip_runtime.h>

#define ZDIM 4096
#define DIN  256
#define DTS  2048
#define DOUT 256
#define CDIM 65536
#define SPLIT 8
#define CHUNK (CDIM / SPLIT)   // 8192 c per chunk = 32 i of 256 j
#define ZP    128              // z rows per block

typedef float fv4 __attribute__((ext_vector_type(4)));
typedef __bf16 bv8 __attribute__((ext_vector_type(8)));
typedef unsigned short u16;
typedef u16 uv8 __attribute__((ext_vector_type(8)));

union BC  { __bf16 b; u16 u; };
union VC8 { uv8 u; bv8 b; };
union FU  { unsigned u; float f; };

static __device__ __forceinline__ u16  f2b(float f){ BC c; c.b=(__bf16)f; return c.u; }
static __device__ __forceinline__ float bu(u16 v){ FU c; c.u = ((unsigned)v) << 16; return c.f; }
static __device__ __forceinline__ bv8  asb(uv8 x){ VC8 c; c.u=x; return c.b; }
static __device__ __forceinline__ uv8  pack8(fv4 a, fv4 b){
  uv8 p;
  p[0]=f2b(a[0]); p[1]=f2b(a[1]); p[2]=f2b(a[2]); p[3]=f2b(a[3]);
  p[4]=f2b(b[0]); p[5]=f2b(b[1]); p[6]=f2b(b[2]); p[7]=f2b(b[3]);
  return p;
}

// ---------------------------------------------------------------------------
// Kernel 1: Kmat[k][c] = sum_t W[k][t] * T[t][c]   (bf16 output in ws)
// memory-bound: streams 512 MB of T once. Unchanged (attribution).
// ---------------------------------------------------------------------------
__global__ __launch_bounds__(512, 2) void k_wt(const float* __restrict__ W,
                                               const float* __restrict__ T,
                                               u16* __restrict__ Km) {
  __shared__ u16 Al[256 * 40];
  __shared__ u16 Bl[32 * 128];
  const int tid  = threadIdx.x;
  const int lane = tid & 63;
  const int wave = tid >> 6;
  const int wk = (wave >> 1) * 64;
  const int wc = (wave & 1) * 64;
  const int cb = blockIdx.x * 128;
  const int ar = lane & 15, tg = lane >> 4;

  fv4 acc[4][4];
#pragma unroll
  for (int m = 0; m < 4; ++m)
#pragma unroll
    for (int n = 0; n < 4; ++n)
#pragma unroll
      for (int r = 0; r < 4; ++r) acc[m][n][r] = 0.f;

  for (int t0 = 0; t0 < DTS; t0 += 32) {
#pragma unroll
    for (int p = 0; p < 2; ++p) {
      int oct = tid + p * 512;
      int kr = oct >> 2, ts = (oct & 3) * 8;
      const float* src = W + (size_t)kr * DTS + t0 + ts;
      fv4 a = *(const fv4*)src, b = *(const fv4*)(src + 4);
      *(uv8*)&Al[kr * 40 + ts] = pack8(a, b);
    }
    {
      int tr = tid >> 4, co = (tid & 15) * 8;
      const float* src = T + (size_t)(t0 + tr) * CDIM + cb + co;
      fv4 a = *(const fv4*)src, b = *(const fv4*)(src + 4);
      *(uv8*)&Bl[tr * 128 + co] = pack8(a, b);
    }
    __syncthreads();
    bv8 af[4];
#pragma unroll
    for (int m = 0; m < 4; ++m)
      af[m] = asb(*(const uv8*)&Al[(wk + m * 16 + ar) * 40 + tg * 8]);
#pragma unroll
    for (int n = 0; n < 4; ++n) {
      uv8 bu2;
#pragma unroll
      for (int e = 0; e < 8; ++e)
        bu2[e] = Bl[(tg * 8 + e) * 128 + wc + n * 16 + ar];
      bv8 bf = asb(bu2);
#pragma unroll
      for (int m = 0; m < 4; ++m)
        acc[m][n] = __builtin_amdgcn_mfma_f32_16x16x32_bf16(af[m], bf, acc[m][n], 0, 0, 0);
    }
    __syncthreads();
  }
#pragma unroll
  for (int m = 0; m < 4; ++m)
#pragma unroll
    for (int n = 0; n < 4; ++n)
#pragma unroll
      for (int r = 0; r < 4; ++r) {
        int kr = wk + m * 16 + tg * 4 + r;
        int cc = cb + wc + n * 16 + ar;
        Km[(size_t)kr * CDIM + cc] = f2b(acc[m][n][r]);
      }
}

// ---------------------------------------------------------------------------
// Kernel 2 v6: out[z,k] = sum_i sum_j (x_i x_j) Km[k, i*256+j]
// z-panel 128, grid 256 = 1 block/CU, SPLIT=8 chunks XCD-affine (s=bid&7):
// all 32 blocks of an XCD read the SAME 16KB stage tile at the same stage
// index -> L2-shared, HBM traffic ~chunk-size not chunk*blocks.
// 8 waves = 2(z) x 4(k); wave tile 64z x 64k; 16 MFMA per barrier.
// acc[4][4] single accumulator; xi (f32, from LDS Xt) folded into A-frag.
// Kl double-buffered, reg-staged: loads issued early, ds_writes after MFMAs.
// ---------------------------------------------------------------------------
__global__ __launch_bounds__(512, 2) void k_bil(const float* __restrict__ X,
                                                const u16* __restrict__ Km,
                                                float* __restrict__ P) {
  __shared__ u16 Kl[2][256 * 36];   // 2 x 18 KB: [k][32 j], pad 36
  __shared__ float Xt[32 * ZP];     // 16 KB: Xt[i][z] = X[z0+z][i0+i]
  const int tid  = threadIdx.x;
  const int lane = tid & 63;
  const int wave = tid >> 6;
  const int wz   = (wave >> 2) * 64;   // z-half
  const int wk   = (wave & 3) * 64;    // k-quarter
  const int bid  = blockIdx.x;
  const int s    = bid & 7;            // chunk -> XCD under RR dispatch
  const int z0   = (bid >> 3) * ZP;
  const int i0   = s * 32;
  const int cs   = s * CHUNK;
  const int ar = lane & 15, tg = lane >> 4;

  // one-time Xt stage (f32 xi for exactness)
  for (int idx = tid; idx < 32 * ZP; idx += 512) {
    int ii = idx >> 7, z = idx & (ZP - 1);
    Xt[idx] = X[(size_t)(z0 + z) * DIN + i0 + ii];
  }

  // A-base fragments: af[m][js] = bf16(x[z0+wz+m*16+ar][js*32+tg*8 .. +8])
  // (compiler may rematerialize from L1 -- X rows are hot)
  uv8 af[4][8];
#pragma unroll
  for (int m = 0; m < 4; ++m) {
    const float* row = X + (size_t)(z0 + wz + m * 16 + ar) * DIN;
#pragma unroll
    for (int js = 0; js < 8; ++js) {
      const float* src = row + js * 32 + tg * 8;
      fv4 a = *(const fv4*)src, b = *(const fv4*)(src + 4);
      af[m][js] = pack8(a, b);
    }
  }

  // B staging map: thread t -> k row t>>1, 16-elem j-seg (t&1)*16
  const int sk = tid >> 1, sj = (tid & 1) * 16;
  const u16* gb = Km + (size_t)sk * CDIM + cs + sj;

  // prologue: stage 0
  {
    uv8 a = *(const uv8*)gb, b = *(const uv8*)(gb + 8);
    *(uv8*)&Kl[0][sk * 36 + sj]     = a;
    *(uv8*)&Kl[0][sk * 36 + sj + 8] = b;
  }
  __syncthreads();

  fv4 acc[4][4];
#pragma unroll
  for (int m = 0; m < 4; ++m)
#pragma unroll
    for (int n = 0; n < 4; ++n)
#pragma unroll
      for (int r = 0; r < 4; ++r) acc[m][n][r] = 0.f;

  int buf = 0;
  for (int i = 0; i < 32; ++i) {
    float xi[4];
#pragma unroll
    for (int m = 0; m < 4; ++m) xi[m] = Xt[i * ZP + wz + m * 16 + ar];
#pragma unroll
    for (int js = 0; js < 8; ++js) {
      const int st = i * 8 + js;
      const bool stg = (st < 255);
      uv8 g0, g1;
      if (stg) {                       // issue next-stage loads early
        const u16* p = gb + (size_t)(st + 1) * 32;
        g0 = *(const uv8*)p;
        g1 = *(const uv8*)(p + 8);
      }
      bv8 bf[4];
#pragma unroll
      for (int n = 0; n < 4; ++n)
        bf[n] = asb(*(const uv8*)&Kl[buf][(wk + n * 16 + ar) * 36 + tg * 8]);
#pragma unroll
      for (int m = 0; m < 4; ++m) {
        uv8 ap;
#pragma unroll
        for (int e = 0; e < 8; ++e) ap[e] = f2b(xi[m] * bu(af[m][js][e]));
        bv8 apb = asb(ap);
#pragma unroll
        for (int n = 0; n < 4; ++n)
          acc[m][n] = __builtin_amdgcn_mfma_f32_16x16x32_bf16(apb, bf[n], acc[m][n], 0, 0, 0);
      }
      if (stg) {                       // write-late into other buffer
        u16* d = &Kl[buf ^ 1][sk * 36 + sj];
        *(uv8*)d       = g0;
        *(uv8*)(d + 8) = g1;
      }
      __syncthreads();
      buf ^= 1;
    }
  }

  float* dst = P + (size_t)s * (ZDIM * DOUT) + (size_t)z0 * DOUT;
#pragma unroll
  for (int m = 0; m < 4; ++m)
#pragma unroll
    for (int n = 0; n < 4; ++n)
#pragma unroll
      for (int r = 0; r < 4; ++r)
        dst[(size_t)(wz + m * 16 + tg * 4 + r) * DOUT + wk + n * 16 + ar] = acc[m][n][r];
}

// ---------------------------------------------------------------------------
// Kernel 3: out[z][k] = sum_s partial[s][z][k]
// ---------------------------------------------------------------------------
__global__ __launch_bounds__(256) void k_red(const float* __restrict__ P,
                                             float* __restrict__ O) {
  size_t idx = ((size_t)blockIdx.x * 256 + threadIdx.x) * 4;
  fv4 acc;
#pragma unroll
  for (int r = 0; r < 4; ++r) acc[r] = 0.f;
#pragma unroll
  for (int p = 0; p < SPLIT; ++p)
    acc += *(const fv4*)&P[(size_t)p * (ZDIM * DOUT) + idx];
  *(fv4*)&O[idx] = acc;
}

extern "C" void kernel_launch(void* const* d_in, const int* in_sizes, int n_in,
                              void* d_out, int out_size, void* d_ws, size_t ws_size,
                              hipStream_t stream) {
  const float* feat = (const float*)d_in[0];   // [4096, 256]
  const float* T    = (const float*)d_in[1];   // [2048, 65536]
  const float* W    = (const float*)d_in[2];   // [256, 2048]
  float* out = (float*)d_out;                  // [4096, 256]

  u16*   Km = (u16*)d_ws;                                        // 32 MB bf16 Kmat
  float* P  = (float*)((char*)d_ws + (size_t)DOUT * CDIM * 2);   // 32 MB partials

  k_wt <<<dim3(512),  dim3(512), 0, stream>>>(W, T, Km);
  k_bil<<<dim3(256),  dim3(512), 0, stream>>>(feat, Km, P);
  k_red<<<dim3(1024), dim3(256), 0, stream>>>(P, out);
}